// Round 1
// baseline (3993.210 us; speedup 1.0000x reference)
//
#include <hip/hip_runtime.h>
#include <cstdint>

static constexpr int B   = 8;
static constexpr int N0  = 4096;
static constexpr int NQ  = 1024;
static constexpr int KNB = 16;

// ---------------------------------------------------------------------------
// prep: split x into coor/normal/plane, compute |c|^2 and f0 = coor@W_in^T+b
// ---------------------------------------------------------------------------
__global__ void prep_kernel(const float* __restrict__ x,
                            const float* __restrict__ W_in,
                            const float* __restrict__ b_in,
                            float* __restrict__ coor, float* __restrict__ nrm,
                            float* __restrict__ pl, float* __restrict__ kk,
                            float* __restrict__ f0) {
  int i = blockIdx.x * 256 + threadIdx.x;
  if (i >= B * N0) return;
  const float* xp = x + (size_t)i * 7;
  float cx = xp[0], cy = xp[1], cz = xp[2];
  coor[i * 3 + 0] = cx; coor[i * 3 + 1] = cy; coor[i * 3 + 2] = cz;
  nrm[i * 3 + 0] = xp[3]; nrm[i * 3 + 1] = xp[4]; nrm[i * 3 + 2] = xp[5];
  pl[i] = xp[6];
  // tie-sensitive (feeds kNN distance): exact fp32, ref association order
  kk[i] = __fadd_rn(__fadd_rn(__fmul_rn(cx, cx), __fmul_rn(cy, cy)), __fmul_rn(cz, cz));
#pragma unroll
  for (int o = 0; o < 8; o++) {
    f0[(size_t)i * 8 + o] = cx * W_in[o * 3 + 0] + cy * W_in[o * 3 + 1] + cz * W_in[o * 3 + 2] + b_in[o];
  }
}

// ---------------------------------------------------------------------------
// kNN: wave per query. Each lane owns M=Nk/64 candidates in registers.
// 16 rounds of wave argmin (tie -> smaller index, matches stable top_k).
// d2 = ((|q|^2 - 2*dot) + |k|^2), exact fp32 non-fused like the reference.
// ---------------------------------------------------------------------------
template <int M>
__global__ void knn_kernel(const float* __restrict__ cq, const float* __restrict__ qq,
                           const float* __restrict__ ck, const float* __restrict__ kk,
                           int Q, int Nk, int* __restrict__ out) {
  int gt = blockIdx.x * 256 + threadIdx.x;
  int bq = gt >> 6;
  int lane = gt & 63;
  int b = bq / Q;
  float qx = cq[(size_t)bq * 3 + 0], qy = cq[(size_t)bq * 3 + 1], qz = cq[(size_t)bq * 3 + 2];
  float q2 = qq[bq];
  const float* ckb = ck + (size_t)b * Nk * 3;
  const float* kkb = kk + (size_t)b * Nk;
  float d[M];
#pragma unroll
  for (int i = 0; i < M; i++) {
    int n = i * 64 + lane;
    float kx = ckb[n * 3 + 0], ky = ckb[n * 3 + 1], kz = ckb[n * 3 + 2];
    float dot = __fadd_rn(__fadd_rn(__fmul_rn(qx, kx), __fmul_rn(qy, ky)), __fmul_rn(qz, kz));
    d[i] = __fadd_rn(__fsub_rn(q2, __fmul_rn(2.0f, dot)), kkb[n]);
  }
  unsigned long long mask = 0ull;
  float lv = 3.0e38f; int li = 0;
#pragma unroll
  for (int i = 0; i < M; i++) { if (d[i] < lv) { lv = d[i]; li = i; } }
  int* op = out + (size_t)bq * KNB;
  for (int r = 0; r < KNB; r++) {
    float v = lv; int n = li * 64 + lane;
#pragma unroll
    for (int off = 32; off; off >>= 1) {
      float ov = __shfl_xor(v, off);
      int   on = __shfl_xor(n, off);
      if (ov < v || (ov == v && on < n)) { v = ov; n = on; }
    }
    if (lane == 0) op[r] = n;
    if ((n & 63) == lane) {  // this lane owned the winner: mark + rescan
      mask |= 1ull << (n >> 6);
      lv = 3.0e38f; li = 0;
#pragma unroll
      for (int i = 0; i < M; i++) {
        bool dead = (mask >> i) & 1ull;
        float dv = dead ? 3.0e38f : d[i];
        if (dv < lv) { lv = dv; li = i; }
      }
    }
  }
}

// ---------------------------------------------------------------------------
// ctrY[b,q,o] = sum_c fq[b,q,c] * W[o, CF+c]   (K-independent half of conv)
// ---------------------------------------------------------------------------
template <int CF, int CO>
__global__ void ctry_kernel(const float* __restrict__ fq, const float* __restrict__ W,
                            float* __restrict__ ctrY, int total) {
  int i = blockIdx.x * 256 + threadIdx.x;
  if (i >= total) return;
  int o = i % CO, bq = i / CO;
  const float* fp = fq + (size_t)bq * CF;
  const float* wp = W + (size_t)o * (2 * CF) + CF;
  float acc = 0.f;
#pragma unroll
  for (int c = 0; c < CF; c++) acc = fmaf(fp[c], wp[c], acc);
  ctrY[i] = acc;
}

// ---------------------------------------------------------------------------
// edge-conv pass A: wave per (b,q); lane = g*16+k (g: o-chunk==GN group, k: nbr)
// computes y = Wl*(nb-ctr) + ctrY; tracks min/max over k per channel; adds
// per-(b,group) sum/sumsq partials (block LDS -> one atomic per block).
// Wl LDS layout skewed by 8 words per group -> conflict-free 4-way broadcast.
// ---------------------------------------------------------------------------
template <int CF, int CO>
__global__ __launch_bounds__(256) void edgeconv_kernel(
    const float* __restrict__ fq, const float* __restrict__ fk,
    const int* __restrict__ knn, const float* __restrict__ Wfull,
    const float* __restrict__ ctrY,
    float* __restrict__ ymin, float* __restrict__ ymax,
    float* __restrict__ gstats, int Q, int Nk) {
  constexpr int J = CO / 4;
  constexpr int SEC = J * CF + 8;
  __shared__ float Wl[4 * SEC];
  __shared__ float sstat[8];
  for (int t = threadIdx.x; t < CO * CF; t += 256) {
    int o = t / CF, c = t % CF;
    Wl[(o / J) * SEC + (o % J) * CF + c] = Wfull[(size_t)o * (2 * CF) + c];
  }
  if (threadIdx.x < 8) sstat[threadIdx.x] = 0.0f;
  __syncthreads();
  const int wid = threadIdx.x >> 6, lane = threadIdx.x & 63;
  const int bq = blockIdx.x * 4 + wid;
  const int b = bq / Q;
  const int g = lane >> 4, k = lane & 15;
  const int ni = knn[(size_t)bq * KNB + k];
  const float* nbp = fk + (size_t)(b * Nk + ni) * CF;
  const float* cp  = fq + (size_t)bq * CF;
  float acc[J];
#pragma unroll
  for (int j = 0; j < J; j++) acc[j] = 0.0f;
  const float* wg = &Wl[g * SEC];
#pragma unroll
  for (int c = 0; c < CF; c += 4) {
    float4 nb4 = *(const float4*)(nbp + c);
    float4 c4  = *(const float4*)(cp + c);
    float e0 = nb4.x - c4.x, e1 = nb4.y - c4.y, e2 = nb4.z - c4.z, e3 = nb4.w - c4.w;
#pragma unroll
    for (int j = 0; j < J; j++) {
      float4 w4 = *(const float4*)(wg + j * CF + c);
      acc[j] = fmaf(e0, w4.x, acc[j]);
      acc[j] = fmaf(e1, w4.y, acc[j]);
      acc[j] = fmaf(e2, w4.z, acc[j]);
      acc[j] = fmaf(e3, w4.w, acc[j]);
    }
  }
  float s = 0.f, s2 = 0.f;
  const float* cyp = ctrY + (size_t)bq * CO + g * J;
#pragma unroll
  for (int j = 0; j < J; j++) {
    float y = acc[j] + cyp[j];
    acc[j] = y;            // acc becomes running max
    s += y; s2 = fmaf(y, y, s2);
  }
  float mn[J];
#pragma unroll
  for (int j = 0; j < J; j++) mn[j] = acc[j];
#pragma unroll
  for (int m = 1; m < 16; m <<= 1) {  // reduce over the 16 k-lanes
#pragma unroll
    for (int j = 0; j < J; j++) {
      float a = __shfl_xor(acc[j], m); if (a > acc[j]) acc[j] = a;
      float c2 = __shfl_xor(mn[j], m); if (c2 < mn[j]) mn[j] = c2;
    }
    s  += __shfl_xor(s, m);
    s2 += __shfl_xor(s2, m);
  }
  if (k == 0) {
    float* mnp = ymin + (size_t)bq * CO + g * J;
    float* mxp = ymax + (size_t)bq * CO + g * J;
#pragma unroll
    for (int j = 0; j < J; j++) { mnp[j] = mn[j]; mxp[j] = acc[j]; }
    atomicAdd(&sstat[g], s);
    atomicAdd(&sstat[4 + g], s2);
  }
  __syncthreads();
  if (threadIdx.x < 8) atomicAdd(&gstats[b * 8 + threadIdx.x], sstat[threadIdx.x]);
}

// ---------------------------------------------------------------------------
// GroupNorm stat finalize: mean + rsqrt(var+eps) per (b,group)
// ---------------------------------------------------------------------------
__global__ void gn_final(const float* __restrict__ gstats, float* __restrict__ gmr,
                         float inv_cnt) {
  int i = threadIdx.x;
  if (i < B * 4) {
    int b = i >> 2, g = i & 3;
    float m  = gstats[b * 8 + g] * inv_cnt;
    float s2 = gstats[b * 8 + 4 + g] * inv_cnt;
    float v = s2 - m * m;
    gmr[i * 2] = m;
    gmr[i * 2 + 1] = rsqrtf(v + 1e-5f);
  }
}

// ---------------------------------------------------------------------------
// pass B: f[b,q,o] = lrelu((sel - m)*gw*rs + gb), sel = max if scale>=0 else min
// (exact: lrelu and positive-scale affine are monotone, so max over K commutes)
// ---------------------------------------------------------------------------
template <int CO>
__global__ void gn_out_kernel(const float* __restrict__ ymin, const float* __restrict__ ymax,
                              const float* __restrict__ gmr, const float* __restrict__ gw,
                              const float* __restrict__ gb, float* __restrict__ fout,
                              int total, int Q) {
  int i = blockIdx.x * 256 + threadIdx.x;
  if (i >= total) return;
  constexpr int J = CO / 4;
  int o = i % CO; int bq = i / CO; int b = bq / Q;
  int g = o / J;
  float m = gmr[(b * 4 + g) * 2], rs = gmr[(b * 4 + g) * 2 + 1];
  float sc = gw[o] * rs;
  float sel = (sc >= 0.f) ? ymax[i] : ymin[i];
  float v = (sel - m) * sc + gb[o];
  fout[i] = (v > 0.f) ? v : 0.2f * v;
}

// ---------------------------------------------------------------------------
// FPS: block per batch; coords in LDS; register min-dists; block argmax with
// first-occurrence (smaller index) tie semantics, matching jnp.argmax.
// ---------------------------------------------------------------------------
template <int NPTS, int BLK>
__global__ __launch_bounds__(BLK) void fps_kernel(const float* __restrict__ coor,
                                                  int* __restrict__ idx_out, int num) {
  constexpr int M = NPTS / BLK;
  constexpr int NW = BLK / 64;
  __shared__ float sx[NPTS], sy[NPTS], sz[NPTS];
  __shared__ float redv[NW];
  __shared__ int   redi[NW];
  __shared__ int s_last;
  const int b = blockIdx.x, tid = threadIdx.x;
  const float* cb = coor + (size_t)b * NPTS * 3;
  for (int n = tid; n < NPTS; n += BLK) {
    sx[n] = cb[n * 3 + 0]; sy[n] = cb[n * 3 + 1]; sz[n] = cb[n * 3 + 2];
  }
  float dist[M];
#pragma unroll
  for (int i = 0; i < M; i++) dist[i] = 3.4e38f;
  if (tid == 0) idx_out[(size_t)b * num] = 0;
  __syncthreads();
  int last = 0;
  for (int t = 1; t < num; t++) {
    float px = sx[last], py = sy[last], pz = sz[last];
    float bv = -1.f; int bi = 0x7fffffff;
#pragma unroll
    for (int i = 0; i < M; i++) {
      int n = tid + i * BLK;
      float dx = __fsub_rn(sx[n], px), dy = __fsub_rn(sy[n], py), dz = __fsub_rn(sz[n], pz);
      float d = __fadd_rn(__fadd_rn(__fmul_rn(dx, dx), __fmul_rn(dy, dy)), __fmul_rn(dz, dz));
      float dd = dist[i]; dd = (d < dd) ? d : dd; dist[i] = dd;
      if (dd > bv) { bv = dd; bi = n; }  // strict > keeps first (smaller n)
    }
#pragma unroll
    for (int off = 32; off; off >>= 1) {
      float ov = __shfl_xor(bv, off); int oi = __shfl_xor(bi, off);
      if (ov > bv || (ov == bv && oi < bi)) { bv = ov; bi = oi; }
    }
    if ((tid & 63) == 0) { redv[tid >> 6] = bv; redi[tid >> 6] = bi; }
    __syncthreads();
    if (tid == 0) {
      float fv = redv[0]; int fi = redi[0];
#pragma unroll
      for (int w = 1; w < NW; w++) {
        float v = redv[w]; int ix = redi[w];
        if (v > fv || (v == fv && ix < fi)) { fv = v; fi = ix; }
      }
      s_last = fi; idx_out[(size_t)b * num + t] = fi;
    }
    __syncthreads();
    last = s_last;
  }
}

// ---------------------------------------------------------------------------
// gather coor/normal/plane/|c|^2/features at FPS indices
// ---------------------------------------------------------------------------
template <int CF>
__global__ void gather_kernel(const int* __restrict__ idx,
                              const float* __restrict__ coor, const float* __restrict__ nrm,
                              const float* __restrict__ pl, const float* __restrict__ kk,
                              const float* __restrict__ f,
                              float* __restrict__ cq, float* __restrict__ nq,
                              float* __restrict__ pq, float* __restrict__ kq,
                              float* __restrict__ fq, int Nsrc, int num) {
  int i = blockIdx.x * 256 + threadIdx.x;
  if (i >= B * num) return;
  int b = i / num;
  int src = b * Nsrc + idx[i];
  cq[i * 3 + 0] = coor[(size_t)src * 3 + 0];
  cq[i * 3 + 1] = coor[(size_t)src * 3 + 1];
  cq[i * 3 + 2] = coor[(size_t)src * 3 + 2];
  nq[i * 3 + 0] = nrm[(size_t)src * 3 + 0];
  nq[i * 3 + 1] = nrm[(size_t)src * 3 + 1];
  nq[i * 3 + 2] = nrm[(size_t)src * 3 + 2];
  pq[i] = pl[src]; kq[i] = kk[src];
#pragma unroll 4
  for (int c = 0; c < CF; c++) fq[(size_t)i * CF + c] = f[(size_t)src * CF + c];
}

// ---------------------------------------------------------------------------
extern "C" void kernel_launch(void* const* d_in, const int* in_sizes, int n_in,
                              void* d_out, int out_size, void* d_ws, size_t ws_size,
                              hipStream_t stream) {
  (void)in_sizes; (void)n_in; (void)out_size; (void)ws_size;
  const float* x    = (const float*)d_in[0];
  const float* W_in = (const float*)d_in[1];
  const float* b_in = (const float*)d_in[2];
  const float* W1   = (const float*)d_in[3];
  const float* g1w  = (const float*)d_in[4];
  const float* g1b  = (const float*)d_in[5];
  const float* W2   = (const float*)d_in[6];
  const float* g2w  = (const float*)d_in[7];
  const float* g2b  = (const float*)d_in[8];
  const float* W3   = (const float*)d_in[9];
  const float* g3w  = (const float*)d_in[10];
  const float* g3b  = (const float*)d_in[11];
  const float* W4   = (const float*)d_in[12];
  const float* g4w  = (const float*)d_in[13];
  const float* g4b  = (const float*)d_in[14];

  float* ws = (float*)d_ws;
  size_t o_coor = 0;
  size_t o_nrm  = o_coor + (size_t)B * N0 * 3;
  size_t o_pl   = o_nrm  + (size_t)B * N0 * 3;
  size_t o_kk0  = o_pl   + (size_t)B * N0;
  size_t o_f0   = o_kk0  + (size_t)B * N0;
  size_t o_f1   = o_f0   + (size_t)B * N0 * 8;
  size_t o_ctrY = o_f1   + (size_t)B * N0 * 32;
  size_t o_ymin = o_ctrY + (size_t)B * N0 * 32;
  size_t o_ymax = o_ymin + (size_t)B * N0 * 32;
  size_t o_knn  = o_ymax + (size_t)B * N0 * 32;             // int region
  size_t o_gst  = o_knn  + (size_t)B * N0 * KNB;
  size_t o_gmr  = o_gst  + 4 * B * 8;
  size_t o_idx1 = o_gmr  + 4 * B * 8;                        // int region
  size_t o_idx2 = o_idx1 + (size_t)B * NQ;                   // int region
  size_t o_cq1  = o_idx2 + (size_t)B * NQ;
  size_t o_nq1  = o_cq1  + (size_t)B * NQ * 3;
  size_t o_pq1  = o_nq1  + (size_t)B * NQ * 3;
  size_t o_kkq1 = o_pq1  + (size_t)B * NQ;
  size_t o_fq1  = o_kkq1 + (size_t)B * NQ;
  size_t o_f2   = o_fq1  + (size_t)B * NQ * 32;
  size_t o_f3   = o_f2   + (size_t)B * NQ * 64;
  size_t o_kkq2 = o_f3   + (size_t)B * NQ * 64;
  size_t o_fq2  = o_kkq2 + (size_t)B * NQ;

  float* coor = ws + o_coor;  float* nrm  = ws + o_nrm;   float* pl   = ws + o_pl;
  float* kk0  = ws + o_kk0;   float* f0   = ws + o_f0;    float* f1   = ws + o_f1;
  float* ctrY = ws + o_ctrY;  float* ymin = ws + o_ymin;  float* ymax = ws + o_ymax;
  int*   knn  = (int*)(ws + o_knn);
  float* gst  = ws + o_gst;   float* gmr  = ws + o_gmr;
  int*   idx1 = (int*)(ws + o_idx1);
  int*   idx2 = (int*)(ws + o_idx2);
  float* cq1  = ws + o_cq1;   float* nq1  = ws + o_nq1;   float* pq1  = ws + o_pq1;
  float* kkq1 = ws + o_kkq1;  float* fq1  = ws + o_fq1;
  float* f2   = ws + o_f2;    float* f3   = ws + o_f3;
  float* kkq2 = ws + o_kkq2;  float* fq2  = ws + o_fq2;

  float* out  = (float*)d_out;
  float* cq2  = out;                                   // (B,NQ,3)
  float* fout = out + (size_t)B * NQ * 3;              // (B,NQ,128)
  float* nq2  = fout + (size_t)B * NQ * 128;           // (B,NQ,3)
  float* pq2  = nq2 + (size_t)B * NQ * 3;              // (B,NQ,1)

  hipMemsetAsync(gst, 0, 4 * B * 8 * sizeof(float), stream);

  // stage 0
  prep_kernel<<<(B * N0 + 255) / 256, 256, 0, stream>>>(x, W_in, b_in, coor, nrm, pl, kk0, f0);

  // ---- layer 1: Q=4096, keys=4096, CF=8, CO=32 ----
  ctry_kernel<8, 32><<<(B * N0 * 32 + 255) / 256, 256, 0, stream>>>(f0, W1, ctrY, B * N0 * 32);
  knn_kernel<64><<<B * N0 * 64 / 256, 256, 0, stream>>>(coor, kk0, coor, kk0, N0, N0, knn);
  edgeconv_kernel<8, 32><<<B * N0 / 4, 256, 0, stream>>>(f0, f0, knn, W1, ctrY, ymin, ymax, gst + 0, N0, N0);
  gn_final<<<1, 64, 0, stream>>>(gst + 0, gmr + 0, 1.0f / (4096.0f * 16.0f * 8.0f));
  gn_out_kernel<32><<<(B * N0 * 32 + 255) / 256, 256, 0, stream>>>(ymin, ymax, gmr + 0, g1w, g1b, f1, B * N0 * 32, N0);

  // FPS 1 + gather
  fps_kernel<4096, 512><<<B, 512, 0, stream>>>(coor, idx1, NQ);
  gather_kernel<32><<<(B * NQ + 255) / 256, 256, 0, stream>>>(idx1, coor, nrm, pl, kk0, f1,
                                                              cq1, nq1, pq1, kkq1, fq1, N0, NQ);

  // ---- layer 2: Q=1024, keys=4096, CF=32, CO=64 ----
  ctry_kernel<32, 64><<<(B * NQ * 64 + 255) / 256, 256, 0, stream>>>(fq1, W2, ctrY, B * NQ * 64);
  knn_kernel<64><<<B * NQ * 64 / 256, 256, 0, stream>>>(cq1, kkq1, coor, kk0, NQ, N0, knn);
  edgeconv_kernel<32, 64><<<B * NQ / 4, 256, 0, stream>>>(fq1, f1, knn, W2, ctrY, ymin, ymax, gst + B * 8, NQ, N0);
  gn_final<<<1, 64, 0, stream>>>(gst + B * 8, gmr + 64, 1.0f / (1024.0f * 16.0f * 16.0f));
  gn_out_kernel<64><<<(B * NQ * 64 + 255) / 256, 256, 0, stream>>>(ymin, ymax, gmr + 64, g2w, g2b, f2, B * NQ * 64, NQ);

  // ---- layer 3: Q=1024, keys=1024, CF=64, CO=64 ----
  ctry_kernel<64, 64><<<(B * NQ * 64 + 255) / 256, 256, 0, stream>>>(f2, W3, ctrY, B * NQ * 64);
  knn_kernel<16><<<B * NQ * 64 / 256, 256, 0, stream>>>(cq1, kkq1, cq1, kkq1, NQ, NQ, knn);
  edgeconv_kernel<64, 64><<<B * NQ / 4, 256, 0, stream>>>(f2, f2, knn, W3, ctrY, ymin, ymax, gst + 2 * B * 8, NQ, NQ);
  gn_final<<<1, 64, 0, stream>>>(gst + 2 * B * 8, gmr + 128, 1.0f / (1024.0f * 16.0f * 16.0f));
  gn_out_kernel<64><<<(B * NQ * 64 + 255) / 256, 256, 0, stream>>>(ymin, ymax, gmr + 128, g3w, g3b, f3, B * NQ * 64, NQ);

  // FPS 2 + gather (coor_q/normal_q/plane_q go straight to d_out)
  fps_kernel<1024, 512><<<B, 512, 0, stream>>>(cq1, idx2, NQ);
  gather_kernel<64><<<(B * NQ + 255) / 256, 256, 0, stream>>>(idx2, cq1, nq1, pq1, kkq1, f3,
                                                              cq2, nq2, pq2, kkq2, fq2, NQ, NQ);

  // ---- layer 4: Q=1024, keys=1024, CF=64, CO=128 ----
  ctry_kernel<64, 128><<<(B * NQ * 128 + 255) / 256, 256, 0, stream>>>(fq2, W4, ctrY, B * NQ * 128);
  knn_kernel<16><<<B * NQ * 64 / 256, 256, 0, stream>>>(cq2, kkq2, cq1, kkq1, NQ, NQ, knn);
  edgeconv_kernel<64, 128><<<B * NQ / 4, 256, 0, stream>>>(fq2, f3, knn, W4, ctrY, ymin, ymax, gst + 3 * B * 8, NQ, NQ);
  gn_final<<<1, 64, 0, stream>>>(gst + 3 * B * 8, gmr + 192, 1.0f / (1024.0f * 16.0f * 32.0f));
  gn_out_kernel<128><<<(B * NQ * 128 + 255) / 256, 256, 0, stream>>>(ymin, ymax, gmr + 192, g4w, g4b, fout, B * NQ * 128, NQ);
}

// Round 2
// 2598.804 us; speedup vs baseline: 1.5366x; 1.5366x over previous
//
#include <hip/hip_runtime.h>
#include <cstdint>

static constexpr int B   = 8;
static constexpr int N0  = 4096;
static constexpr int NQ  = 1024;
static constexpr int KNB = 16;

// ---------------------------------------------------------------------------
// prep: split x into coor/normal/plane, compute |c|^2 and f0 = coor@W_in^T+b
// ---------------------------------------------------------------------------
__global__ void prep_kernel(const float* __restrict__ x,
                            const float* __restrict__ W_in,
                            const float* __restrict__ b_in,
                            float* __restrict__ coor, float* __restrict__ nrm,
                            float* __restrict__ pl, float* __restrict__ kk,
                            float* __restrict__ f0) {
  int i = blockIdx.x * 256 + threadIdx.x;
  if (i >= B * N0) return;
  const float* xp = x + (size_t)i * 7;
  float cx = xp[0], cy = xp[1], cz = xp[2];
  coor[i * 3 + 0] = cx; coor[i * 3 + 1] = cy; coor[i * 3 + 2] = cz;
  nrm[i * 3 + 0] = xp[3]; nrm[i * 3 + 1] = xp[4]; nrm[i * 3 + 2] = xp[5];
  pl[i] = xp[6];
  // tie-sensitive (feeds kNN distance): exact fp32, ref association order
  kk[i] = __fadd_rn(__fadd_rn(__fmul_rn(cx, cx), __fmul_rn(cy, cy)), __fmul_rn(cz, cz));
#pragma unroll
  for (int o = 0; o < 8; o++) {
    f0[(size_t)i * 8 + o] = cx * W_in[o * 3 + 0] + cy * W_in[o * 3 + 1] + cz * W_in[o * 3 + 2] + b_in[o];
  }
}

// ---------------------------------------------------------------------------
// kNN: wave per query. Each lane owns M=Nk/64 candidates in registers.
// 16 rounds of wave argmin (tie -> smaller index, matches stable top_k).
// d2 = ((|q|^2 - 2*dot) + |k|^2), exact fp32 non-fused like the reference.
// ---------------------------------------------------------------------------
template <int M>
__global__ void knn_kernel(const float* __restrict__ cq, const float* __restrict__ qq,
                           const float* __restrict__ ck, const float* __restrict__ kk,
                           int Q, int Nk, int* __restrict__ out) {
  int gt = blockIdx.x * 256 + threadIdx.x;
  int bq = gt >> 6;
  int lane = gt & 63;
  int b = bq / Q;
  float qx = cq[(size_t)bq * 3 + 0], qy = cq[(size_t)bq * 3 + 1], qz = cq[(size_t)bq * 3 + 2];
  float q2 = qq[bq];
  const float* ckb = ck + (size_t)b * Nk * 3;
  const float* kkb = kk + (size_t)b * Nk;
  float d[M];
#pragma unroll
  for (int i = 0; i < M; i++) {
    int n = i * 64 + lane;
    float kx = ckb[n * 3 + 0], ky = ckb[n * 3 + 1], kz = ckb[n * 3 + 2];
    float dot = __fadd_rn(__fadd_rn(__fmul_rn(qx, kx), __fmul_rn(qy, ky)), __fmul_rn(qz, kz));
    d[i] = __fadd_rn(__fsub_rn(q2, __fmul_rn(2.0f, dot)), kkb[n]);
  }
  unsigned long long mask = 0ull;
  float lv = 3.0e38f; int li = 0;
#pragma unroll
  for (int i = 0; i < M; i++) { if (d[i] < lv) { lv = d[i]; li = i; } }
  int* op = out + (size_t)bq * KNB;
  for (int r = 0; r < KNB; r++) {
    float v = lv; int n = li * 64 + lane;
#pragma unroll
    for (int off = 32; off; off >>= 1) {
      float ov = __shfl_xor(v, off);
      int   on = __shfl_xor(n, off);
      if (ov < v || (ov == v && on < n)) { v = ov; n = on; }
    }
    if (lane == 0) op[r] = n;
    if ((n & 63) == lane) {  // this lane owned the winner: mark + rescan
      mask |= 1ull << (n >> 6);
      lv = 3.0e38f; li = 0;
#pragma unroll
      for (int i = 0; i < M; i++) {
        bool dead = (mask >> i) & 1ull;
        float dv = dead ? 3.0e38f : d[i];
        if (dv < lv) { lv = dv; li = i; }
      }
    }
  }
}

// ---------------------------------------------------------------------------
// ctrY[b,q,o] = sum_c fq[b,q,c] * W[o, CF+c]   (K-independent half of conv)
// ---------------------------------------------------------------------------
template <int CF, int CO>
__global__ void ctry_kernel(const float* __restrict__ fq, const float* __restrict__ W,
                            float* __restrict__ ctrY, int total) {
  int i = blockIdx.x * 256 + threadIdx.x;
  if (i >= total) return;
  int o = i % CO, bq = i / CO;
  const float* fp = fq + (size_t)bq * CF;
  const float* wp = W + (size_t)o * (2 * CF) + CF;
  float acc = 0.f;
#pragma unroll
  for (int c = 0; c < CF; c++) acc = fmaf(fp[c], wp[c], acc);
  ctrY[i] = acc;
}

// ---------------------------------------------------------------------------
// edge-conv pass A: wave per (b,q); lane = g*16+k (g: o-chunk==GN group, k: nbr)
// computes y = Wl*(nb-ctr) + ctrY; tracks min/max over k per channel; adds
// per-(b,group) sum/sumsq partials (block LDS -> one atomic per block).
// ---------------------------------------------------------------------------
template <int CF, int CO>
__global__ __launch_bounds__(256) void edgeconv_kernel(
    const float* __restrict__ fq, const float* __restrict__ fk,
    const int* __restrict__ knn, const float* __restrict__ Wfull,
    const float* __restrict__ ctrY,
    float* __restrict__ ymin, float* __restrict__ ymax,
    float* __restrict__ gstats, int Q, int Nk) {
  constexpr int J = CO / 4;
  constexpr int SEC = J * CF + 8;
  __shared__ float Wl[4 * SEC];
  __shared__ float sstat[8];
  for (int t = threadIdx.x; t < CO * CF; t += 256) {
    int o = t / CF, c = t % CF;
    Wl[(o / J) * SEC + (o % J) * CF + c] = Wfull[(size_t)o * (2 * CF) + c];
  }
  if (threadIdx.x < 8) sstat[threadIdx.x] = 0.0f;
  __syncthreads();
  const int wid = threadIdx.x >> 6, lane = threadIdx.x & 63;
  const int bq = blockIdx.x * 4 + wid;
  const int b = bq / Q;
  const int g = lane >> 4, k = lane & 15;
  const int ni = knn[(size_t)bq * KNB + k];
  const float* nbp = fk + (size_t)(b * Nk + ni) * CF;
  const float* cp  = fq + (size_t)bq * CF;
  float acc[J];
#pragma unroll
  for (int j = 0; j < J; j++) acc[j] = 0.0f;
  const float* wg = &Wl[g * SEC];
#pragma unroll
  for (int c = 0; c < CF; c += 4) {
    float4 nb4 = *(const float4*)(nbp + c);
    float4 c4  = *(const float4*)(cp + c);
    float e0 = nb4.x - c4.x, e1 = nb4.y - c4.y, e2 = nb4.z - c4.z, e3 = nb4.w - c4.w;
#pragma unroll
    for (int j = 0; j < J; j++) {
      float4 w4 = *(const float4*)(wg + j * CF + c);
      acc[j] = fmaf(e0, w4.x, acc[j]);
      acc[j] = fmaf(e1, w4.y, acc[j]);
      acc[j] = fmaf(e2, w4.z, acc[j]);
      acc[j] = fmaf(e3, w4.w, acc[j]);
    }
  }
  float s = 0.f, s2 = 0.f;
  const float* cyp = ctrY + (size_t)bq * CO + g * J;
#pragma unroll
  for (int j = 0; j < J; j++) {
    float y = acc[j] + cyp[j];
    acc[j] = y;            // acc becomes running max
    s += y; s2 = fmaf(y, y, s2);
  }
  float mn[J];
#pragma unroll
  for (int j = 0; j < J; j++) mn[j] = acc[j];
#pragma unroll
  for (int m = 1; m < 16; m <<= 1) {  // reduce over the 16 k-lanes
#pragma unroll
    for (int j = 0; j < J; j++) {
      float a = __shfl_xor(acc[j], m); if (a > acc[j]) acc[j] = a;
      float c2 = __shfl_xor(mn[j], m); if (c2 < mn[j]) mn[j] = c2;
    }
    s  += __shfl_xor(s, m);
    s2 += __shfl_xor(s2, m);
  }
  if (k == 0) {
    float* mnp = ymin + (size_t)bq * CO + g * J;
    float* mxp = ymax + (size_t)bq * CO + g * J;
#pragma unroll
    for (int j = 0; j < J; j++) { mnp[j] = mn[j]; mxp[j] = acc[j]; }
    atomicAdd(&sstat[g], s);
    atomicAdd(&sstat[4 + g], s2);
  }
  __syncthreads();
  if (threadIdx.x < 8) atomicAdd(&gstats[b * 8 + threadIdx.x], sstat[threadIdx.x]);
}

// ---------------------------------------------------------------------------
// pass B (gn_final fused): m/rs computed per-thread from gstats;
// f = lrelu((sel - m)*gw*rs + gb), sel = max if scale>=0 else min.
// ---------------------------------------------------------------------------
template <int CO>
__global__ void gn_out_kernel(const float* __restrict__ ymin, const float* __restrict__ ymax,
                              const float* __restrict__ gstats, const float* __restrict__ gw,
                              const float* __restrict__ gb, float* __restrict__ fout,
                              int total, int Q, float inv_cnt) {
  int i = blockIdx.x * 256 + threadIdx.x;
  if (i >= total) return;
  constexpr int J = CO / 4;
  int o = i % CO; int bq = i / CO; int b = bq / Q;
  int g = o / J;
  float m  = gstats[b * 8 + g] * inv_cnt;
  float s2 = gstats[b * 8 + 4 + g] * inv_cnt;
  float rs = rsqrtf(s2 - m * m + 1e-5f);
  float sc = gw[o] * rs;
  float sel = (sc >= 0.f) ? ymax[i] : ymin[i];
  float v = (sel - m) * sc + gb[o];
  fout[i] = (v > 0.f) ? v : 0.2f * v;
}

// ---------------------------------------------------------------------------
// FPS v2: block per batch, BLK=256. Owned coords live in REGISTERS (no per-iter
// coord LDS reads). Candidate packed as u64 key (dist_bits<<12)|(4095-n):
// unsigned max == (max dist, tie -> min index) exactly (dists >= 0).
// One barrier per iteration: ping-pong wave slots + redundant final reduce in
// all lanes (no tid0 serialization, no broadcast round-trip).
// ---------------------------------------------------------------------------
template <int NPTS, int BLK>
__global__ __launch_bounds__(BLK) void fps_kernel(const float* __restrict__ coor,
                                                  int* __restrict__ idx_out, int num) {
  constexpr int M = NPTS / BLK;
  constexpr int NW = BLK / 64;
  __shared__ float sx[NPTS], sy[NPTS], sz[NPTS];
  __shared__ unsigned long long slot[2][NW];
  const int b = blockIdx.x, tid = threadIdx.x;
  const int wid = tid >> 6;
  const float* cb = coor + (size_t)b * NPTS * 3;
  for (int n = tid; n < NPTS; n += BLK) {
    sx[n] = cb[n * 3 + 0]; sy[n] = cb[n * 3 + 1]; sz[n] = cb[n * 3 + 2];
  }
  if (tid == 0) idx_out[(size_t)b * num] = 0;
  __syncthreads();
  float cx[M], cy[M], cz[M], dist[M];
#pragma unroll
  for (int i = 0; i < M; i++) {
    int n = tid + i * BLK;
    cx[i] = sx[n]; cy[i] = sy[n]; cz[i] = sz[n];
    dist[i] = 3.4e38f;
  }
  float px = sx[0], py = sy[0], pz = sz[0];
  for (int t = 1; t < num; t++) {
    // update min-dists + local argmax (strict > keeps smallest n; i ascending)
    float bv = -1.f; int bi = tid;
#pragma unroll
    for (int i = 0; i < M; i++) {
      float dx = __fsub_rn(cx[i], px), dy = __fsub_rn(cy[i], py), dz = __fsub_rn(cz[i], pz);
      float d = __fadd_rn(__fadd_rn(__fmul_rn(dx, dx), __fmul_rn(dy, dy)), __fmul_rn(dz, dz));
      float dd = dist[i]; dd = (d < dd) ? d : dd; dist[i] = dd;
      if (dd > bv) { bv = dd; bi = tid + i * BLK; }
    }
    unsigned long long bk =
        ((unsigned long long)__float_as_uint(bv) << 12) | (unsigned)(4095 - bi);
    // wave butterfly on packed key
#pragma unroll
    for (int off = 32; off; off >>= 1) {
      unsigned long long ok = __shfl_xor(bk, off);
      if (ok > bk) bk = ok;
    }
    if ((tid & 63) == 0) slot[t & 1][wid] = bk;
    __syncthreads();
#pragma unroll
    for (int w = 0; w < NW; w++) {
      unsigned long long k2 = slot[t & 1][w];
      if (k2 > bk) bk = k2;
    }
    int win = 4095 - (int)(bk & 0xFFFull);
    px = sx[win]; py = sy[win]; pz = sz[win];
    if (tid == 0) idx_out[(size_t)b * num + t] = win;
  }
}

// ---------------------------------------------------------------------------
// gather coor/normal/plane/|c|^2/features at FPS indices
// ---------------------------------------------------------------------------
template <int CF>
__global__ void gather_kernel(const int* __restrict__ idx,
                              const float* __restrict__ coor, const float* __restrict__ nrm,
                              const float* __restrict__ pl, const float* __restrict__ kk,
                              const float* __restrict__ f,
                              float* __restrict__ cq, float* __restrict__ nq,
                              float* __restrict__ pq, float* __restrict__ kq,
                              float* __restrict__ fq, int Nsrc, int num) {
  int i = blockIdx.x * 256 + threadIdx.x;
  if (i >= B * num) return;
  int b = i / num;
  int src = b * Nsrc + idx[i];
  cq[i * 3 + 0] = coor[(size_t)src * 3 + 0];
  cq[i * 3 + 1] = coor[(size_t)src * 3 + 1];
  cq[i * 3 + 2] = coor[(size_t)src * 3 + 2];
  nq[i * 3 + 0] = nrm[(size_t)src * 3 + 0];
  nq[i * 3 + 1] = nrm[(size_t)src * 3 + 1];
  nq[i * 3 + 2] = nrm[(size_t)src * 3 + 2];
  pq[i] = pl[src]; kq[i] = kk[src];
#pragma unroll 4
  for (int c = 0; c < CF; c++) fq[(size_t)i * CF + c] = f[(size_t)src * CF + c];
}

// ---------------------------------------------------------------------------
extern "C" void kernel_launch(void* const* d_in, const int* in_sizes, int n_in,
                              void* d_out, int out_size, void* d_ws, size_t ws_size,
                              hipStream_t stream) {
  (void)in_sizes; (void)n_in; (void)out_size; (void)ws_size;
  const float* x    = (const float*)d_in[0];
  const float* W_in = (const float*)d_in[1];
  const float* b_in = (const float*)d_in[2];
  const float* W1   = (const float*)d_in[3];
  const float* g1w  = (const float*)d_in[4];
  const float* g1b  = (const float*)d_in[5];
  const float* W2   = (const float*)d_in[6];
  const float* g2w  = (const float*)d_in[7];
  const float* g2b  = (const float*)d_in[8];
  const float* W3   = (const float*)d_in[9];
  const float* g3w  = (const float*)d_in[10];
  const float* g3b  = (const float*)d_in[11];
  const float* W4   = (const float*)d_in[12];
  const float* g4w  = (const float*)d_in[13];
  const float* g4b  = (const float*)d_in[14];

  float* ws = (float*)d_ws;
  size_t o_coor = 0;
  size_t o_nrm  = o_coor + (size_t)B * N0 * 3;
  size_t o_pl   = o_nrm  + (size_t)B * N0 * 3;
  size_t o_kk0  = o_pl   + (size_t)B * N0;
  size_t o_f0   = o_kk0  + (size_t)B * N0;
  size_t o_f1   = o_f0   + (size_t)B * N0 * 8;
  size_t o_ctrY = o_f1   + (size_t)B * N0 * 32;
  size_t o_ymin = o_ctrY + (size_t)B * N0 * 32;
  size_t o_ymax = o_ymin + (size_t)B * N0 * 32;
  size_t o_knn  = o_ymax + (size_t)B * N0 * 32;             // int region
  size_t o_gst  = o_knn  + (size_t)B * N0 * KNB;
  size_t o_idx1 = o_gst  + 4 * B * 8;                        // int region
  size_t o_idx2 = o_idx1 + (size_t)B * NQ;                   // int region
  size_t o_cq1  = o_idx2 + (size_t)B * NQ;
  size_t o_nq1  = o_cq1  + (size_t)B * NQ * 3;
  size_t o_pq1  = o_nq1  + (size_t)B * NQ * 3;
  size_t o_kkq1 = o_pq1  + (size_t)B * NQ;
  size_t o_fq1  = o_kkq1 + (size_t)B * NQ;
  size_t o_f2   = o_fq1  + (size_t)B * NQ * 32;
  size_t o_f3   = o_f2   + (size_t)B * NQ * 64;
  size_t o_kkq2 = o_f3   + (size_t)B * NQ * 64;
  size_t o_fq2  = o_kkq2 + (size_t)B * NQ;

  float* coor = ws + o_coor;  float* nrm  = ws + o_nrm;   float* pl   = ws + o_pl;
  float* kk0  = ws + o_kk0;   float* f0   = ws + o_f0;    float* f1   = ws + o_f1;
  float* ctrY = ws + o_ctrY;  float* ymin = ws + o_ymin;  float* ymax = ws + o_ymax;
  int*   knn  = (int*)(ws + o_knn);
  float* gst  = ws + o_gst;
  int*   idx1 = (int*)(ws + o_idx1);
  int*   idx2 = (int*)(ws + o_idx2);
  float* cq1  = ws + o_cq1;   float* nq1  = ws + o_nq1;   float* pq1  = ws + o_pq1;
  float* kkq1 = ws + o_kkq1;  float* fq1  = ws + o_fq1;
  float* f2   = ws + o_f2;    float* f3   = ws + o_f3;
  float* kkq2 = ws + o_kkq2;  float* fq2  = ws + o_fq2;

  float* out  = (float*)d_out;
  float* cq2  = out;                                   // (B,NQ,3)
  float* fout = out + (size_t)B * NQ * 3;              // (B,NQ,128)
  float* nq2  = fout + (size_t)B * NQ * 128;           // (B,NQ,3)
  float* pq2  = nq2 + (size_t)B * NQ * 3;              // (B,NQ,1)

  hipMemsetAsync(gst, 0, 4 * B * 8 * sizeof(float), stream);

  // stage 0
  prep_kernel<<<(B * N0 + 255) / 256, 256, 0, stream>>>(x, W_in, b_in, coor, nrm, pl, kk0, f0);

  // ---- layer 1: Q=4096, keys=4096, CF=8, CO=32 ----
  ctry_kernel<8, 32><<<(B * N0 * 32 + 255) / 256, 256, 0, stream>>>(f0, W1, ctrY, B * N0 * 32);
  knn_kernel<64><<<B * N0 * 64 / 256, 256, 0, stream>>>(coor, kk0, coor, kk0, N0, N0, knn);
  edgeconv_kernel<8, 32><<<B * N0 / 4, 256, 0, stream>>>(f0, f0, knn, W1, ctrY, ymin, ymax, gst + 0, N0, N0);
  gn_out_kernel<32><<<(B * N0 * 32 + 255) / 256, 256, 0, stream>>>(ymin, ymax, gst + 0, g1w, g1b, f1, B * N0 * 32, N0, 1.0f / (4096.0f * 16.0f * 8.0f));

  // FPS 1 + gather
  fps_kernel<4096, 256><<<B, 256, 0, stream>>>(coor, idx1, NQ);
  gather_kernel<32><<<(B * NQ + 255) / 256, 256, 0, stream>>>(idx1, coor, nrm, pl, kk0, f1,
                                                              cq1, nq1, pq1, kkq1, fq1, N0, NQ);

  // ---- layer 2: Q=1024, keys=4096, CF=32, CO=64 ----
  ctry_kernel<32, 64><<<(B * NQ * 64 + 255) / 256, 256, 0, stream>>>(fq1, W2, ctrY, B * NQ * 64);
  knn_kernel<64><<<B * NQ * 64 / 256, 256, 0, stream>>>(cq1, kkq1, coor, kk0, NQ, N0, knn);
  edgeconv_kernel<32, 64><<<B * NQ / 4, 256, 0, stream>>>(fq1, f1, knn, W2, ctrY, ymin, ymax, gst + B * 8, NQ, N0);
  gn_out_kernel<64><<<(B * NQ * 64 + 255) / 256, 256, 0, stream>>>(ymin, ymax, gst + B * 8, g2w, g2b, f2, B * NQ * 64, NQ, 1.0f / (1024.0f * 16.0f * 16.0f));

  // ---- layer 3: Q=1024, keys=1024, CF=64, CO=64 ----
  ctry_kernel<64, 64><<<(B * NQ * 64 + 255) / 256, 256, 0, stream>>>(f2, W3, ctrY, B * NQ * 64);
  knn_kernel<16><<<B * NQ * 64 / 256, 256, 0, stream>>>(cq1, kkq1, cq1, kkq1, NQ, NQ, knn);
  edgeconv_kernel<64, 64><<<B * NQ / 4, 256, 0, stream>>>(f2, f2, knn, W3, ctrY, ymin, ymax, gst + 2 * B * 8, NQ, NQ);
  gn_out_kernel<64><<<(B * NQ * 64 + 255) / 256, 256, 0, stream>>>(ymin, ymax, gst + 2 * B * 8, g3w, g3b, f3, B * NQ * 64, NQ, 1.0f / (1024.0f * 16.0f * 16.0f));

  // FPS 2 + gather (coor_q/normal_q/plane_q go straight to d_out)
  fps_kernel<1024, 256><<<B, 256, 0, stream>>>(cq1, idx2, NQ);
  gather_kernel<64><<<(B * NQ + 255) / 256, 256, 0, stream>>>(idx2, cq1, nq1, pq1, kkq1, f3,
                                                              cq2, nq2, pq2, kkq2, fq2, NQ, NQ);

  // ---- layer 4: Q=1024, keys=1024, CF=64, CO=128 ----
  ctry_kernel<64, 128><<<(B * NQ * 128 + 255) / 256, 256, 0, stream>>>(fq2, W4, ctrY, B * NQ * 128);
  knn_kernel<16><<<B * NQ * 64 / 256, 256, 0, stream>>>(cq2, kkq2, cq1, kkq1, NQ, NQ, knn);
  edgeconv_kernel<64, 128><<<B * NQ / 4, 256, 0, stream>>>(fq2, f3, knn, W4, ctrY, ymin, ymax, gst + 3 * B * 8, NQ, NQ);
  gn_out_kernel<128><<<(B * NQ * 128 + 255) / 256, 256, 0, stream>>>(ymin, ymax, gst + 3 * B * 8, g4w, g4b, fout, B * NQ * 128, NQ, 1.0f / (1024.0f * 16.0f * 32.0f));
}